// Round 1
// 579.292 us; speedup vs baseline: 1.0800x; 1.0800x over previous
//
#include <hip/hip_runtime.h>
#include <cstdint>

#define DIM   128
#define NH    4
#define WSZ   7
#define NTOK  49
#define SHIFT 3
#define HIMG  56
#define BATCH 64
#define LTOK  3136
#define HID   512
#define EPSF  1e-5f

typedef short bf16x8 __attribute__((ext_vector_type(8)));
typedef float f32x4  __attribute__((ext_vector_type(4)));

__device__ __forceinline__ float bf2f(ushort u){ return __uint_as_float(((uint32_t)u)<<16); }
__device__ __forceinline__ ushort f2bf(float f){
  uint32_t u = __float_as_uint(f);
  u += 0x7FFFu + ((u>>16)&1u);
  return (ushort)(u>>16);
}
__device__ __forceinline__ float wred(float v){
  #pragma unroll
  for (int off=32; off; off>>=1) v += __shfl_xor(v, off, 64);
  return v;
}

// ---- fused weight transpose+convert (single launch): dst[c*R + r] = bf16(src[r*Cc + c])
__global__ __launch_bounds__(256) void transpose_cvt_all(
    const float* __restrict__ qkvw, const float* __restrict__ pw,
    const float* __restrict__ f1w,  const float* __restrict__ f2w,
    ushort* __restrict__ ws)
{
  int bid = blockIdx.x;
  const float* src; ushort* dst; int R, Cc, b0;
  if (bid < 192)      { src = qkvw; dst = ws;          R = 128; Cc = 384; b0 = 0;   }
  else if (bid < 256) { src = pw;   dst = ws + 49152;  R = 128; Cc = 128; b0 = 192; }
  else if (bid < 512) { src = f1w;  dst = ws + 65536;  R = 128; Cc = 512; b0 = 256; }
  else                { src = f2w;  dst = ws + 131072; R = 512; Cc = 128; b0 = 512; }
  int idx = (bid - b0)*256 + threadIdx.x;
  int c = idx / R, r = idx % R;                 // writes coalesced, reads strided (L2)
  dst[idx] = f2bf(src[r*Cc + c]);
}

// LDS layout (ushort units), 25072 ush = 50144 B -> 3 blocks/CU (was 62464 B -> 2):
//  [OFF_BUFA, +8704)  64x136 : xw(LN1) -> V^T [128 dims][68 toks] -> attn-out[64][136] -> xn[64][136]
//  [OFF_QK,   +15680) Q,K per head stride 40 ; P overlay per head (stride 72, full k<64 written)
//                     then LN2 partials (f32) ; then hchunk[64][136] for MLP
//  [OFF_TBL,  +676)   rel-bias table bf16 (+pad; head-3 pad-row overreads stay in-bounds)
#define OFF_BUFA 0
#define OFF_QK   8704
#define QKSTR    40
#define OFF_TBL  (OFF_QK + 8*NTOK*QKSTR)   // 24384
#define SMEM_SZ  25072

__global__ __launch_bounds__(256,3) void swin_block_kernel(
    const float* __restrict__ x, const float* __restrict__ n1g, const float* __restrict__ n1b,
    const ushort* __restrict__ qkv_wt, const float* __restrict__ qkvb,
    const float* __restrict__ bias_tbl, const ushort* __restrict__ proj_wt,
    const float* __restrict__ projb,
    const float* __restrict__ n2g, const float* __restrict__ n2b,
    const ushort* __restrict__ fc1_wt, const float* __restrict__ fc1b,
    const ushort* __restrict__ fc2_wt, const float* __restrict__ fc2b,
    float* __restrict__ out)
{
  __shared__ ushort smem[SMEM_SZ];

  const int tid  = threadIdx.x;
  const int wave = tid >> 6;
  const int lane = tid & 63;
  const int b_   = blockIdx.x;
  const int b    = b_ >> 6;
  const int win  = b_ & 63;
  const int wi   = win >> 3, wj = win & 7;

  const int ncol  = lane & 15;
  const int quad  = lane >> 4;
  const int koff  = quad * 8;
  const int rbase = quad * 4;

  // ---- init: rel-bias table only (pad rows/tokens are handled by masking, not pre-zeroing) ----
  for (int i = tid; i < 676; i += 256) smem[OFF_TBL + i] = f2bf(bias_tbl[i]);

  // ---- Phase 0: LN1 on gathered (shifted) window rows ----
  {
    const int c = lane*2;
    const float g0 = n1g[c], g1 = n1g[c+1], be0 = n1b[c], be1 = n1b[c+1];
    for (int r = wave; r < NTOK; r += 4){
      int ti = r / 7, tj = r % 7;
      int hh = (wi*7 + ti + SHIFT) % HIMG;
      int ww = (wj*7 + tj + SHIFT) % HIMG;
      size_t base = ((size_t)b * LTOK + hh*HIMG + ww) * DIM;
      float2 tv = *(const float2*)(x + base + c);
      float v0 = tv.x, v1 = tv.y;
      float mu = wred(v0 + v1) * (1.0f/128.0f);
      float d0 = v0-mu, d1 = v1-mu;
      float rstd = rsqrtf(wred(d0*d0 + d1*d1)*(1.0f/128.0f) + EPSF);
      smem[OFF_BUFA + r*136 + c]   = f2bf(d0*rstd*g0 + be0);
      smem[OFF_BUFA + r*136 + c+1] = f2bf(d1*rstd*g1 + be1);
    }
  }
  __syncthreads();   // B1

  // ---- Phase 1: QKV GEMM (64x384, K=128); V^T goes into bufA (xw dead after afrag) ----
  {
    bf16x8 afrag[4][4];
    #pragma unroll
    for (int mt=0; mt<4; mt++)
      #pragma unroll
      for (int kb=0; kb<4; kb++)
        afrag[mt][kb] = *(const bf16x8*)&smem[OFF_BUFA + (mt*16 + ncol)*136 + kb*32 + koff];
    __syncthreads();   // B2: all afrags register-resident; bufA reusable as V^T

    // zero V^T pad tokens 49..63 (PV consumes token range [0,64))
    for (int i = tid; i < 128*15; i += 256){
      int dd = i/15, t = 49 + i%15;
      smem[OFF_BUFA + dd*68 + t] = 0;
    }

    #pragma unroll
    for (int nt=0; nt<6; nt++){
      int c = wave*96 + nt*16 + ncol;
      int which = c >> 7, head = (c >> 5) & 3, d = c & 31;
      bf16x8 bfrag[4];
      #pragma unroll
      for (int kb=0; kb<4; kb++) bfrag[kb] = *(const bf16x8*)(qkv_wt + (size_t)c*128 + kb*32 + koff);
      float bias = qkvb[c];
      int qkb = OFF_QK + (head*2 + which)*NTOK*QKSTR + d;
      int vb  = OFF_BUFA + (head*32 + d)*68;
      #pragma unroll
      for (int mt=0; mt<4; mt++){
        f32x4 acc = {0.f,0.f,0.f,0.f};
        #pragma unroll
        for (int kb=0; kb<4; kb++)
          acc = __builtin_amdgcn_mfma_f32_16x16x32_bf16(afrag[mt][kb], bfrag[kb], acc, 0,0,0);
        #pragma unroll
        for (int r=0; r<4; r++){
          int m = mt*16 + rbase + r;
          if (m < NTOK){
            ushort v = f2bf(acc[r] + bias);
            if (which == 2) smem[vb + m] = v;
            else            smem[qkb + m*QKSTR] = v;
          }
        }
      }
    }
  }
  __syncthreads();   // B3

  // ---- Phase 2: MFMA attention, wave = head ----
  {
    const int h = wave;
    const int qbase = OFF_QK + (h*2    )*NTOK*QKSTR;
    const int kbase = OFF_QK + (h*2 + 1)*NTOK*QKSTR;
    const int pbase = qbase;                       // P overlays Q+K (dead after frag loads), stride 72

    bf16x8 qf[4], kf[4];
    #pragma unroll
    for (int mt=0; mt<4; mt++) qf[mt] = *(const bf16x8*)&smem[qbase + (mt*16 + ncol)*QKSTR + koff];
    #pragma unroll
    for (int nt=0; nt<4; nt++) kf[nt] = *(const bf16x8*)&smem[kbase + (nt*16 + ncol)*QKSTR + koff];

    f32x4 s[4][4];
    #pragma unroll
    for (int mt=0; mt<4; mt++)
      #pragma unroll
      for (int nt=0; nt<4; nt++){
        f32x4 z = {0.f,0.f,0.f,0.f};
        s[mt][nt] = __builtin_amdgcn_mfma_f32_16x16x32_bf16(qf[mt], kf[nt], z, 0,0,0);
      }

    int kcol[4], rm[4];
    #pragma unroll
    for (int nt=0; nt<4; nt++){
      int k = nt*16 + ncol;
      kcol[nt] = k;
      int kc = k < NTOK ? k : 48;
      int si = kc/7, sj = kc%7;
      int sh = wi*7 + si, sw = wj*7 + sj;
      rm[nt] = (sh<49?0:(sh<53?1:2))*3 + (sw<49?0:(sw<53?1:2));
    }
    const float scale = 0.17677669529663687f;  // 1/sqrt(32)

    // softmax WITHOUT max-subtract: |S| <~ 2 for this model; masked lanes -> exp -> 0.
    #pragma unroll
    for (int mt=0; mt<4; mt++){
      #pragma unroll
      for (int r=0; r<4; r++){
        int m  = mt*16 + rbase + r;
        int mc = m < NTOK ? m : 48;
        int ti = mc/7, tj = mc%7;
        int habs = wi*7 + ti, wabs = wj*7 + tj;
        int rn = (habs<49?0:(habs<53?1:2))*3 + (wabs<49?0:(wabs<53?1:2));
        float sv[4];
        #pragma unroll
        for (int nt=0; nt<4; nt++){
          int k  = kcol[nt];
          int kc = k < NTOK ? k : 48;
          int si = kc/7, sj = kc%7;
          int idx = (ti - si + 6)*13 + (tj - sj + 6);
          float bias = bf2f(smem[OFF_TBL + idx*4 + h]);
          float v = s[mt][nt][r]*scale + bias + (rn == rm[nt] ? 0.f : -100.f);
          sv[nt] = (k < NTOK) ? v : -1e30f;
        }
        float sum = 0.f;
        #pragma unroll
        for (int nt=0; nt<4; nt++){ sv[nt] = __expf(sv[nt]); sum += sv[nt]; }
        #pragma unroll
        for (int off=1; off<16; off<<=1) sum += __shfl_xor(sum, off, 64);
        float rs = 1.0f/sum;
        #pragma unroll
        for (int nt=0; nt<4; nt++) s[mt][nt][r] = sv[nt]*rs;
      }
    }

    // P store: stride 72, ALL k in [0,64) written (k>=49 are exact zeros) -> PV never
    // reads unwritten bytes for valid rows (NaN-safe), no cross-row overread.
    #pragma unroll
    for (int mt=0; mt<4; mt++)
      #pragma unroll
      for (int r=0; r<4; r++){
        int m = mt*16 + rbase + r;
        if (m < NTOK){
          #pragma unroll
          for (int nt=0; nt<4; nt++)
            smem[pbase + m*72 + kcol[nt]] = f2bf(s[mt][nt][r]);
        }
      }

    bf16x8 vf[2][2];
    #pragma unroll
    for (int nt=0; nt<2; nt++)
      #pragma unroll
      for (int kq=0; kq<2; kq++)
        vf[nt][kq] = *(const bf16x8*)&smem[OFF_BUFA + (h*32 + nt*16 + ncol)*68 + kq*32 + koff];
    __syncthreads();   // B4: all waves hold vf; P stores drained; bufA free for attn-out

    f32x4 o[4][2];
    #pragma unroll
    for (int mt=0; mt<4; mt++)
      #pragma unroll
      for (int nt=0; nt<2; nt++){ f32x4 z={0.f,0.f,0.f,0.f}; o[mt][nt]=z; }

    #pragma unroll
    for (int mt=0; mt<4; mt++)
      #pragma unroll
      for (int kq=0; kq<2; kq++){
        bf16x8 pf = *(const bf16x8*)&smem[pbase + (mt*16 + ncol)*72 + kq*32 + koff];
        #pragma unroll
        for (int nt=0; nt<2; nt++)
          o[mt][nt] = __builtin_amdgcn_mfma_f32_16x16x32_bf16(pf, vf[nt][kq], o[mt][nt], 0,0,0);
      }

    #pragma unroll
    for (int mt=0; mt<4; mt++)
      #pragma unroll
      for (int nt=0; nt<2; nt++)
        #pragma unroll
        for (int r=0; r<4; r++){
          int m = mt*16 + rbase + r;
          if (m < NTOK)
            smem[OFF_BUFA + m*136 + h*32 + nt*16 + ncol] = f2bf(o[mt][nt][r]);
        }
  }
  __syncthreads();   // B5

  // ---- Phase 3: proj GEMM (64x128, K=128) + residual -> x2 kept in REGISTERS ----
  // (proj output (nt,mt,r)->(m,j) mapping is identical to the final residual's, so no LDS buffer)
  float x2reg[2][4][4];
  {
    bf16x8 afrag[4][4];
    #pragma unroll
    for (int mt=0; mt<4; mt++)
      #pragma unroll
      for (int kb=0; kb<4; kb++)
        afrag[mt][kb] = *(const bf16x8*)&smem[OFF_BUFA + (mt*16 + ncol)*136 + kb*32 + koff];

    #pragma unroll
    for (int nt=0; nt<2; nt++){
      int j = wave*32 + nt*16 + ncol;
      bf16x8 bfrag[4];
      #pragma unroll
      for (int kb=0; kb<4; kb++) bfrag[kb] = *(const bf16x8*)(proj_wt + (size_t)j*128 + kb*32 + koff);
      float bias = projb[j];
      #pragma unroll
      for (int mt=0; mt<4; mt++){
        f32x4 acc = {0.f,0.f,0.f,0.f};
        #pragma unroll
        for (int kb=0; kb<4; kb++)
          acc = __builtin_amdgcn_mfma_f32_16x16x32_bf16(afrag[mt][kb], bfrag[kb], acc, 0,0,0);
        #pragma unroll
        for (int r=0; r<4; r++){
          int m = mt*16 + rbase + r;
          if (m < NTOK){
            int ti = m/7, tj = m%7;
            int hh = (wi*7 + ti + SHIFT) % HIMG;
            int ww = (wj*7 + tj + SHIFT) % HIMG;
            size_t addr = ((size_t)b*LTOK + hh*HIMG + ww)*DIM + j;
            x2reg[nt][mt][r] = acc[r] + bias + x[addr];
          } else x2reg[nt][mt][r] = 0.f;   // keep pad rows NaN-free
        }
      }
    }
  }

  // ---- Phase 3.5: LN2 partial sums (16-lane shfl reduce -> f32 table in dead Q/K region) ----
  float2* pp = (float2*)&smem[OFF_QK];          // pp[m*4 + wave] = {sum, sumsq} over that wave's 32 cols
  #pragma unroll
  for (int mt=0; mt<4; mt++)
    #pragma unroll
    for (int r=0; r<4; r++){
      float a0 = x2reg[0][mt][r], a1 = x2reg[1][mt][r];
      float sm = a0 + a1, sq = a0*a0 + a1*a1;
      #pragma unroll
      for (int off=1; off<16; off<<=1){ sm += __shfl_xor(sm, off, 64); sq += __shfl_xor(sq, off, 64); }
      if (ncol == 0) pp[(mt*16 + rbase + r)*4 + wave] = make_float2(sm, sq);
    }
  __syncthreads();   // B6

  // ---- Phase 4: LN2 finalize + write xn (bf16) into bufA (attn-out dead) ----
  {
    const int j0 = wave*32 + ncol, j1 = j0 + 16;
    const float g0 = n2g[j0], be0 = n2b[j0], g1 = n2g[j1], be1 = n2b[j1];
    #pragma unroll
    for (int mt=0; mt<4; mt++)
      #pragma unroll
      for (int r=0; r<4; r++){
        int m = mt*16 + rbase + r;
        f32x4 pa = *(const f32x4*)&pp[m*4];
        f32x4 pb = *(const f32x4*)&pp[m*4 + 2];
        float sm = pa[0]+pa[2]+pb[0]+pb[2];
        float sq = pa[1]+pa[3]+pb[1]+pb[3];
        float mu   = sm * (1.0f/128.0f);
        float rstd = rsqrtf(sq*(1.0f/128.0f) - mu*mu + EPSF);
        smem[OFF_BUFA + m*136 + j0] = f2bf((x2reg[0][mt][r]-mu)*rstd*g0 + be0);
        smem[OFF_BUFA + m*136 + j1] = f2bf((x2reg[1][mt][r]-mu)*rstd*g1 + be1);
      }
  }
  __syncthreads();   // B7

  // ---- Phase 5: MLP tiled over 4 hidden chunks of 128; hchunk overlays Q/K region ----
  f32x4 o2[2][4];
  #pragma unroll
  for (int nt=0; nt<2; nt++)
    #pragma unroll
    for (int mt=0; mt<4; mt++){ f32x4 z={0.f,0.f,0.f,0.f}; o2[nt][mt]=z; }

  for (int hk=0; hk<4; hk++){
    #pragma unroll
    for (int nt=0; nt<2; nt++){
      int cloc = wave*32 + nt*16 + ncol;
      int c = hk*128 + cloc;
      bf16x8 bfrag[4];
      #pragma unroll
      for (int kb=0; kb<4; kb++)
        bfrag[kb] = *(const bf16x8*)(fc1_wt + (size_t)c*128 + kb*32 + koff);
      float bias = fc1b[c];
      #pragma unroll
      for (int mt=0; mt<4; mt++){
        f32x4 acc = {0.f,0.f,0.f,0.f};
        #pragma unroll
        for (int kb=0; kb<4; kb++){
          bf16x8 a = *(const bf16x8*)&smem[OFF_BUFA + (mt*16 + ncol)*136 + kb*32 + koff];
          acc = __builtin_amdgcn_mfma_f32_16x16x32_bf16(a, bfrag[kb], acc, 0,0,0);
        }
        #pragma unroll
        for (int r=0; r<4; r++){
          int m = mt*16 + rbase + r;
          if (mt < 3 || m < NTOK){        // skip erf+store for pad rows (outputs discarded)
            float v = acc[r] + bias;
            float g = 0.5f*v*(1.0f + erff(v*0.70710678118654752f));
            smem[OFF_QK + m*136 + cloc] = f2bf(g);
          }
        }
      }
    }
    __syncthreads();

    #pragma unroll
    for (int nt=0; nt<2; nt++){
      int j = wave*32 + nt*16 + ncol;
      bf16x8 bfrag[4];
      #pragma unroll
      for (int kb=0; kb<4; kb++)
        bfrag[kb] = *(const bf16x8*)(fc2_wt + (size_t)j*512 + hk*128 + kb*32 + koff);
      #pragma unroll
      for (int mt=0; mt<4; mt++){
        #pragma unroll
        for (int kb=0; kb<4; kb++){
          bf16x8 a = *(const bf16x8*)&smem[OFF_QK + (mt*16 + ncol)*136 + kb*32 + koff];
          o2[nt][mt] = __builtin_amdgcn_mfma_f32_16x16x32_bf16(a, bfrag[kb], o2[nt][mt], 0,0,0);
        }
      }
    }
    if (hk < 3) __syncthreads();
  }

  // ---- Final: out = x2(reg) + fc2 + b2, un-shift scatter (f32) ----
  #pragma unroll
  for (int nt=0; nt<2; nt++){
    int j = wave*32 + nt*16 + ncol;
    float bias = fc2b[j];
    #pragma unroll
    for (int mt=0; mt<4; mt++){
      #pragma unroll
      for (int r=0; r<4; r++){
        int m = mt*16 + rbase + r;
        if (m < NTOK){
          int ti = m/7, tj = m%7;
          int hh = (wi*7 + ti + SHIFT) % HIMG;
          int ww = (wj*7 + tj + SHIFT) % HIMG;
          size_t addr = ((size_t)b*LTOK + hh*HIMG + ww)*DIM + j;
          out[addr] = o2[nt][mt][r] + bias + x2reg[nt][mt][r];
        }
      }
    }
  }
}

extern "C" void kernel_launch(void* const* d_in, const int* in_sizes, int n_in,
                              void* d_out, int out_size, void* d_ws, size_t ws_size,
                              hipStream_t stream)
{
  const float* x    = (const float*)d_in[0];
  const float* n1g  = (const float*)d_in[1];
  const float* n1b  = (const float*)d_in[2];
  const float* qkvw = (const float*)d_in[3];
  const float* qkvb = (const float*)d_in[4];
  const float* tbl  = (const float*)d_in[5];
  const float* pw   = (const float*)d_in[6];
  const float* pb   = (const float*)d_in[7];
  const float* n2g  = (const float*)d_in[8];
  const float* n2b  = (const float*)d_in[9];
  const float* f1w  = (const float*)d_in[10];
  const float* f1b  = (const float*)d_in[11];
  const float* f2w  = (const float*)d_in[12];
  const float* f2b  = (const float*)d_in[13];

  // Workspace: transposed bf16 weights only (393,216 B).
  ushort* wsbase = (ushort*)d_ws;
  // qkv_wt = ws+0 [384][128]; proj_wt = +49152 [128][128]; fc1_wt = +65536 [512][128]; fc2_wt = +131072 [128][512]

  transpose_cvt_all<<<768, 256, 0, stream>>>(qkvw, pw, f1w, f2w, wsbase);

  swin_block_kernel<<<4096, 256, 0, stream>>>(x, n1g, n1b, wsbase, qkvb, tbl,
                                              wsbase + 49152, pb, n2g, n2b,
                                              wsbase + 65536, f1b, wsbase + 131072, f2b,
                                              (float*)d_out);
}

// Round 2
// 531.260 us; speedup vs baseline: 1.1776x; 1.0904x over previous
//
#include <hip/hip_runtime.h>
#include <cstdint>

#define DIM   128
#define NH    4
#define WSZ   7
#define NTOK  49
#define SHIFT 3
#define HIMG  56
#define BATCH 64
#define LTOK  3136
#define HID   512
#define EPSF  1e-5f

typedef short bf16x8 __attribute__((ext_vector_type(8)));
typedef float f32x4  __attribute__((ext_vector_type(4)));

__device__ __forceinline__ float bf2f(ushort u){ return __uint_as_float(((uint32_t)u)<<16); }
__device__ __forceinline__ ushort f2bf(float f){
  uint32_t u = __float_as_uint(f);
  u += 0x7FFFu + ((u>>16)&1u);
  return (ushort)(u>>16);
}
__device__ __forceinline__ float wred(float v){
  #pragma unroll
  for (int off=32; off; off>>=1) v += __shfl_xor(v, off, 64);
  return v;
}

// ---- fused weight transpose+convert (single launch): dst[c*R + r] = bf16(src[r*Cc + c])
__global__ __launch_bounds__(256) void transpose_cvt_all(
    const float* __restrict__ qkvw, const float* __restrict__ pw,
    const float* __restrict__ f1w,  const float* __restrict__ f2w,
    ushort* __restrict__ ws)
{
  int bid = blockIdx.x;
  const float* src; ushort* dst; int R, Cc, b0;
  if (bid < 192)      { src = qkvw; dst = ws;          R = 128; Cc = 384; b0 = 0;   }
  else if (bid < 256) { src = pw;   dst = ws + 49152;  R = 128; Cc = 128; b0 = 192; }
  else if (bid < 512) { src = f1w;  dst = ws + 65536;  R = 128; Cc = 512; b0 = 256; }
  else                { src = f2w;  dst = ws + 131072; R = 512; Cc = 128; b0 = 512; }
  int idx = (bid - b0)*256 + threadIdx.x;
  int c = idx / R, r = idx % R;                 // writes coalesced, reads strided (L2)
  dst[idx] = f2bf(src[r*Cc + c]);
}

// LDS layout (ushort units), 25072 ush = 50144 B -> 3 blocks/CU:
//  [OFF_BUFA, +8704)  64x136 : xw(LN1) -> V^T [128 dims][68 toks] -> attn-out[64][136] -> xn[64][136]
//  [OFF_QK,   +15680) Q,K per head stride 40 ; P overlay per head (stride 72)
//                     -> xstage f32 [49][132] (12936 ush) + LN2 partials f32x2 (784 ush at +12936)
//                     -> hchunk[64][136] for MLP -> fout f32 [49][132] for coalesced store
//  [OFF_TBL,  +676)   rel-bias table bf16 (+pad; head-3 pad-row overreads stay in-bounds)
#define OFF_BUFA 0
#define OFF_QK   8704
#define QKSTR    40
#define OFF_TBL  (OFF_QK + 8*NTOK*QKSTR)   // 24384
#define OFF_PP   (OFF_QK + 12936)
#define SMEM_SZ  25072

__global__ __launch_bounds__(256,3) void swin_block_kernel(
    const float* __restrict__ x, const float* __restrict__ n1g, const float* __restrict__ n1b,
    const ushort* __restrict__ qkv_wt, const float* __restrict__ qkvb,
    const float* __restrict__ bias_tbl, const ushort* __restrict__ proj_wt,
    const float* __restrict__ projb,
    const float* __restrict__ n2g, const float* __restrict__ n2b,
    const ushort* __restrict__ fc1_wt, const float* __restrict__ fc1b,
    const ushort* __restrict__ fc2_wt, const float* __restrict__ fc2b,
    float* __restrict__ out)
{
  __shared__ ushort smem[SMEM_SZ];

  const int tid  = threadIdx.x;
  const int wave = tid >> 6;
  const int lane = tid & 63;
  const int b_   = blockIdx.x;
  const int b    = b_ >> 6;
  const int win  = b_ & 63;
  const int wi   = win >> 3, wj = win & 7;

  const int ncol  = lane & 15;
  const int quad  = lane >> 4;
  const int koff  = quad * 8;
  const int rbase = quad * 4;
  const int l32   = lane & 31;
  const int hlf   = lane >> 5;

  // ---- init: rel-bias table only ----
  for (int i = tid; i < 676; i += 256) smem[OFF_TBL + i] = f2bf(bias_tbl[i]);

  // ---- Phase 0: LN1 on gathered (shifted) window rows ----
  {
    const int c = lane*2;
    const float g0 = n1g[c], g1 = n1g[c+1], be0 = n1b[c], be1 = n1b[c+1];
    for (int r = wave; r < NTOK; r += 4){
      int ti = r / 7, tj = r % 7;
      int hh = (wi*7 + ti + SHIFT) % HIMG;
      int ww = (wj*7 + tj + SHIFT) % HIMG;
      size_t base = ((size_t)b * LTOK + hh*HIMG + ww) * DIM;
      float2 tv = *(const float2*)(x + base + c);
      float v0 = tv.x, v1 = tv.y;
      float mu = wred(v0 + v1) * (1.0f/128.0f);
      float d0 = v0-mu, d1 = v1-mu;
      float rstd = rsqrtf(wred(d0*d0 + d1*d1)*(1.0f/128.0f) + EPSF);
      smem[OFF_BUFA + r*136 + c]   = f2bf(d0*rstd*g0 + be0);
      smem[OFF_BUFA + r*136 + c+1] = f2bf(d1*rstd*g1 + be1);
    }
  }
  __syncthreads();   // B1

  // ---- Phase 1: QKV GEMM (64x384, K=128); V^T goes into bufA (xw dead after afrag) ----
  {
    bf16x8 afrag[4][4];
    #pragma unroll
    for (int mt=0; mt<4; mt++)
      #pragma unroll
      for (int kb=0; kb<4; kb++)
        afrag[mt][kb] = *(const bf16x8*)&smem[OFF_BUFA + (mt*16 + ncol)*136 + kb*32 + koff];
    __syncthreads();   // B2: afrags register-resident; bufA reusable as V^T

    // zero V^T pad tokens 49..63
    for (int i = tid; i < 128*15; i += 256){
      int dd = i/15, t = 49 + i%15;
      smem[OFF_BUFA + dd*68 + t] = 0;
    }

    #pragma unroll
    for (int nt=0; nt<6; nt++){
      int c = wave*96 + nt*16 + ncol;
      int which = c >> 7, head = (c >> 5) & 3, d = c & 31;
      bf16x8 bfrag[4];
      #pragma unroll
      for (int kb=0; kb<4; kb++) bfrag[kb] = *(const bf16x8*)(qkv_wt + (size_t)c*128 + kb*32 + koff);
      float bias = qkvb[c];
      int qkb = OFF_QK + (head*2 + which)*NTOK*QKSTR + d;
      int vb  = OFF_BUFA + (head*32 + d)*68;
      #pragma unroll
      for (int mt=0; mt<4; mt++){
        f32x4 acc = {0.f,0.f,0.f,0.f};
        #pragma unroll
        for (int kb=0; kb<4; kb++)
          acc = __builtin_amdgcn_mfma_f32_16x16x32_bf16(afrag[mt][kb], bfrag[kb], acc, 0,0,0);
        #pragma unroll
        for (int r=0; r<4; r++){
          int m = mt*16 + rbase + r;
          if (m < NTOK){
            ushort v = f2bf(acc[r] + bias);
            if (which == 2) smem[vb + m] = v;
            else            smem[qkb + m*QKSTR] = v;
          }
        }
      }
    }
  }
  __syncthreads();   // B3

  // ---- Phase 2: MFMA attention, wave = head ----
  {
    const int h = wave;
    const int qbase = OFF_QK + (h*2    )*NTOK*QKSTR;
    const int kbase = OFF_QK + (h*2 + 1)*NTOK*QKSTR;
    const int pbase = qbase;                       // P overlays Q+K, stride 72

    bf16x8 qf[4], kf[4];
    #pragma unroll
    for (int mt=0; mt<4; mt++) qf[mt] = *(const bf16x8*)&smem[qbase + (mt*16 + ncol)*QKSTR + koff];
    #pragma unroll
    for (int nt=0; nt<4; nt++) kf[nt] = *(const bf16x8*)&smem[kbase + (nt*16 + ncol)*QKSTR + koff];

    f32x4 s[4][4];
    #pragma unroll
    for (int mt=0; mt<4; mt++)
      #pragma unroll
      for (int nt=0; nt<4; nt++){
        f32x4 z = {0.f,0.f,0.f,0.f};
        s[mt][nt] = __builtin_amdgcn_mfma_f32_16x16x32_bf16(qf[mt], kf[nt], z, 0,0,0);
      }

    int kcol[4], rm[4];
    #pragma unroll
    for (int nt=0; nt<4; nt++){
      int k = nt*16 + ncol;
      kcol[nt] = k;
      int kc = k < NTOK ? k : 48;
      int si = kc/7, sj = kc%7;
      int sh = wi*7 + si, sw = wj*7 + sj;
      rm[nt] = (sh<49?0:(sh<53?1:2))*3 + (sw<49?0:(sw<53?1:2));
    }
    const float scale = 0.17677669529663687f;  // 1/sqrt(32)

    // softmax WITHOUT max-subtract: |S| <~ 2 here; masked lanes -> exp -> 0.
    #pragma unroll
    for (int mt=0; mt<4; mt++){
      #pragma unroll
      for (int r=0; r<4; r++){
        int m  = mt*16 + rbase + r;
        int mc = m < NTOK ? m : 48;
        int ti = mc/7, tj = mc%7;
        int habs = wi*7 + ti, wabs = wj*7 + tj;
        int rn = (habs<49?0:(habs<53?1:2))*3 + (wabs<49?0:(wabs<53?1:2));
        float sv[4];
        #pragma unroll
        for (int nt=0; nt<4; nt++){
          int k  = kcol[nt];
          int kc = k < NTOK ? k : 48;
          int si = kc/7, sj = kc%7;
          int idx = (ti - si + 6)*13 + (tj - sj + 6);
          float bias = bf2f(smem[OFF_TBL + idx*4 + h]);
          float v = s[mt][nt][r]*scale + bias + (rn == rm[nt] ? 0.f : -100.f);
          sv[nt] = (k < NTOK) ? v : -1e30f;
        }
        float sum = 0.f;
        #pragma unroll
        for (int nt=0; nt<4; nt++){ sv[nt] = __expf(sv[nt]); sum += sv[nt]; }
        #pragma unroll
        for (int off=1; off<16; off<<=1) sum += __shfl_xor(sum, off, 64);
        float rs = 1.0f/sum;
        #pragma unroll
        for (int nt=0; nt<4; nt++) s[mt][nt][r] = sv[nt]*rs;
      }
    }

    // P store: stride 72, ALL k in [0,64) written (k>=49 exact zeros)
    #pragma unroll
    for (int mt=0; mt<4; mt++)
      #pragma unroll
      for (int r=0; r<4; r++){
        int m = mt*16 + rbase + r;
        if (m < NTOK){
          #pragma unroll
          for (int nt=0; nt<4; nt++)
            smem[pbase + m*72 + kcol[nt]] = f2bf(s[mt][nt][r]);
        }
      }

    bf16x8 vf[2][2];
    #pragma unroll
    for (int nt=0; nt<2; nt++)
      #pragma unroll
      for (int kq=0; kq<2; kq++)
        vf[nt][kq] = *(const bf16x8*)&smem[OFF_BUFA + (h*32 + nt*16 + ncol)*68 + kq*32 + koff];
    __syncthreads();   // B4: vf held; P drained; bufA free for attn-out

    f32x4 o[4][2];
    #pragma unroll
    for (int mt=0; mt<4; mt++)
      #pragma unroll
      for (int nt=0; nt<2; nt++){ f32x4 z={0.f,0.f,0.f,0.f}; o[mt][nt]=z; }

    #pragma unroll
    for (int mt=0; mt<4; mt++)
      #pragma unroll
      for (int kq=0; kq<2; kq++){
        bf16x8 pf = *(const bf16x8*)&smem[pbase + (mt*16 + ncol)*72 + kq*32 + koff];
        #pragma unroll
        for (int nt=0; nt<2; nt++)
          o[mt][nt] = __builtin_amdgcn_mfma_f32_16x16x32_bf16(pf, vf[nt][kq], o[mt][nt], 0,0,0);
      }

    #pragma unroll
    for (int mt=0; mt<4; mt++)
      #pragma unroll
      for (int nt=0; nt<2; nt++)
        #pragma unroll
        for (int r=0; r<4; r++){
          int m = mt*16 + rbase + r;
          if (m < NTOK)
            smem[OFF_BUFA + m*136 + h*32 + nt*16 + ncol] = f2bf(o[mt][nt][r]);
        }
  }
  __syncthreads();   // B5

  // ---- Phase 3a: coalesced stage of shifted x rows -> xstage f32 [49][132] (P region dead) ----
  float* xstage = (float*)&smem[OFF_QK];
  {
    for (int rr = wave*2 + hlf; rr < NTOK; rr += 8){
      int ti = rr/7, tj = rr%7;
      int hh = (wi*7 + ti + SHIFT) % HIMG;
      int ww = (wj*7 + tj + SHIFT) % HIMG;
      float4 v = *(const float4*)(x + ((size_t)b*LTOK + hh*HIMG + ww)*DIM + l32*4);
      *(float4*)&xstage[rr*132 + l32*4] = v;
    }
  }

  // ---- Phase 3b: proj GEMM (64x128, K=128) + residual from xstage -> x2 in REGISTERS ----
  float x2reg[2][4][4];
  {
    bf16x8 afrag[4][4];
    #pragma unroll
    for (int mt=0; mt<4; mt++)
      #pragma unroll
      for (int kb=0; kb<4; kb++)
        afrag[mt][kb] = *(const bf16x8*)&smem[OFF_BUFA + (mt*16 + ncol)*136 + kb*32 + koff];
    __syncthreads();   // B5b: xstage visible; afrag register-resident

    #pragma unroll
    for (int nt=0; nt<2; nt++){
      int j = wave*32 + nt*16 + ncol;
      bf16x8 bfrag[4];
      #pragma unroll
      for (int kb=0; kb<4; kb++) bfrag[kb] = *(const bf16x8*)(proj_wt + (size_t)j*128 + kb*32 + koff);
      float bias = projb[j];
      #pragma unroll
      for (int mt=0; mt<4; mt++){
        f32x4 acc = {0.f,0.f,0.f,0.f};
        #pragma unroll
        for (int kb=0; kb<4; kb++)
          acc = __builtin_amdgcn_mfma_f32_16x16x32_bf16(afrag[mt][kb], bfrag[kb], acc, 0,0,0);
        #pragma unroll
        for (int r=0; r<4; r++){
          int m = mt*16 + rbase + r;
          if (m < NTOK) x2reg[nt][mt][r] = acc[r] + bias + xstage[m*132 + j];
          else          x2reg[nt][mt][r] = 0.f;
        }
      }
    }
  }

  // ---- Phase 3.5: LN2 partial sums (16-lane shfl reduce -> f32 table behind xstage) ----
  float2* pp = (float2*)&smem[OFF_PP];          // pp[m*4 + wave] = {sum, sumsq}
  #pragma unroll
  for (int mt=0; mt<4; mt++)
    #pragma unroll
    for (int r=0; r<4; r++){
      float a0 = x2reg[0][mt][r], a1 = x2reg[1][mt][r];
      float sm = a0 + a1, sq = a0*a0 + a1*a1;
      #pragma unroll
      for (int off=1; off<16; off<<=1){ sm += __shfl_xor(sm, off, 64); sq += __shfl_xor(sq, off, 64); }
      if (ncol == 0) pp[(mt*16 + rbase + r)*4 + wave] = make_float2(sm, sq);
    }
  __syncthreads();   // B6

  // ---- Phase 4: LN2 finalize + write xn (bf16) into bufA ----
  {
    const int j0 = wave*32 + ncol, j1 = j0 + 16;
    const float g0 = n2g[j0], be0 = n2b[j0], g1 = n2g[j1], be1 = n2b[j1];
    #pragma unroll
    for (int mt=0; mt<4; mt++)
      #pragma unroll
      for (int r=0; r<4; r++){
        int m = mt*16 + rbase + r;
        f32x4 pa = *(const f32x4*)&pp[m*4];
        f32x4 pb = *(const f32x4*)&pp[m*4 + 2];
        float sm = pa[0]+pa[2]+pb[0]+pb[2];
        float sq = pa[1]+pa[3]+pb[1]+pb[3];
        float mu   = sm * (1.0f/128.0f);
        float rstd = rsqrtf(sq*(1.0f/128.0f) - mu*mu + EPSF);
        smem[OFF_BUFA + m*136 + j0] = f2bf((x2reg[0][mt][r]-mu)*rstd*g0 + be0);
        smem[OFF_BUFA + m*136 + j1] = f2bf((x2reg[1][mt][r]-mu)*rstd*g1 + be1);
      }
  }
  __syncthreads();   // B7

  // ---- Phase 5: MLP tiled over 4 hidden chunks of 128; hchunk overlays Q/K region ----
  f32x4 o2[2][4];
  #pragma unroll
  for (int nt=0; nt<2; nt++)
    #pragma unroll
    for (int mt=0; mt<4; mt++){ f32x4 z={0.f,0.f,0.f,0.f}; o2[nt][mt]=z; }

  for (int hk=0; hk<4; hk++){
    #pragma unroll
    for (int nt=0; nt<2; nt++){
      int cloc = wave*32 + nt*16 + ncol;
      int c = hk*128 + cloc;
      bf16x8 bfrag[4];
      #pragma unroll
      for (int kb=0; kb<4; kb++)
        bfrag[kb] = *(const bf16x8*)(fc1_wt + (size_t)c*128 + kb*32 + koff);
      float bias = fc1b[c];
      #pragma unroll
      for (int mt=0; mt<4; mt++){
        f32x4 acc = {0.f,0.f,0.f,0.f};
        #pragma unroll
        for (int kb=0; kb<4; kb++){
          bf16x8 a = *(const bf16x8*)&smem[OFF_BUFA + (mt*16 + ncol)*136 + kb*32 + koff];
          acc = __builtin_amdgcn_mfma_f32_16x16x32_bf16(a, bfrag[kb], acc, 0,0,0);
        }
        #pragma unroll
        for (int r=0; r<4; r++){
          int m = mt*16 + rbase + r;
          if (mt < 3 || m < NTOK){        // skip erf+store for pad rows
            float v = acc[r] + bias;
            float g = 0.5f*v*(1.0f + erff(v*0.70710678118654752f));
            smem[OFF_QK + m*136 + cloc] = f2bf(g);
          }
        }
      }
    }
    __syncthreads();

    #pragma unroll
    for (int nt=0; nt<2; nt++){
      int j = wave*32 + nt*16 + ncol;
      bf16x8 bfrag[4];
      #pragma unroll
      for (int kb=0; kb<4; kb++)
        bfrag[kb] = *(const bf16x8*)(fc2_wt + (size_t)j*512 + hk*128 + kb*32 + koff);
      #pragma unroll
      for (int mt=0; mt<4; mt++){
        #pragma unroll
        for (int kb=0; kb<4; kb++){
          bf16x8 a = *(const bf16x8*)&smem[OFF_QK + (mt*16 + ncol)*136 + kb*32 + koff];
          o2[nt][mt] = __builtin_amdgcn_mfma_f32_16x16x32_bf16(a, bfrag[kb], o2[nt][mt], 0,0,0);
        }
      }
    }
    __syncthreads();   // also guards fout overlay on last iter
  }

  // ---- Final: fout = x2(reg) + fc2 + b2 into LDS f32 [49][132], then coalesced row store ----
  float* fout = (float*)&smem[OFF_QK];
  #pragma unroll
  for (int nt=0; nt<2; nt++){
    int j = wave*32 + nt*16 + ncol;
    float bias = fc2b[j];
    #pragma unroll
    for (int mt=0; mt<4; mt++){
      #pragma unroll
      for (int r=0; r<4; r++){
        int m = mt*16 + rbase + r;
        if (m < NTOK)
          fout[m*132 + j] = o2[nt][mt][r] + bias + x2reg[nt][mt][r];
      }
    }
  }
  __syncthreads();   // B8

  for (int rr = wave*2 + hlf; rr < NTOK; rr += 8){
    int ti = rr/7, tj = rr%7;
    int hh = (wi*7 + ti + SHIFT) % HIMG;
    int ww = (wj*7 + tj + SHIFT) % HIMG;
    float4 v = *(const float4*)&fout[rr*132 + l32*4];
    *(float4*)(out + ((size_t)b*LTOK + hh*HIMG + ww)*DIM + l32*4) = v;
  }
}

extern "C" void kernel_launch(void* const* d_in, const int* in_sizes, int n_in,
                              void* d_out, int out_size, void* d_ws, size_t ws_size,
                              hipStream_t stream)
{
  const float* x    = (const float*)d_in[0];
  const float* n1g  = (const float*)d_in[1];
  const float* n1b  = (const float*)d_in[2];
  const float* qkvw = (const float*)d_in[3];
  const float* qkvb = (const float*)d_in[4];
  const float* tbl  = (const float*)d_in[5];
  const float* pw   = (const float*)d_in[6];
  const float* pb   = (const float*)d_in[7];
  const float* n2g  = (const float*)d_in[8];
  const float* n2b  = (const float*)d_in[9];
  const float* f1w  = (const float*)d_in[10];
  const float* f1b  = (const float*)d_in[11];
  const float* f2w  = (const float*)d_in[12];
  const float* f2b  = (const float*)d_in[13];

  ushort* wsbase = (ushort*)d_ws;
  transpose_cvt_all<<<768, 256, 0, stream>>>(qkvw, pw, f1w, f2w, wsbase);

  swin_block_kernel<<<4096, 256, 0, stream>>>(x, n1g, n1b, wsbase, qkvb, tbl,
                                              wsbase + 49152, pb, n2g, n2b,
                                              wsbase + 65536, f1b, wsbase + 131072, f2b,
                                              (float*)d_out);
}

// Round 3
// 486.886 us; speedup vs baseline: 1.2849x; 1.0911x over previous
//
#include <hip/hip_runtime.h>
#include <cstdint>

#define DIM   128
#define NH    4
#define WSZ   7
#define NTOK  49
#define SHIFT 3
#define HIMG  56
#define BATCH 64
#define LTOK  3136
#define HID   512
#define EPSF  1e-5f

typedef short bf16x8 __attribute__((ext_vector_type(8)));
typedef float f32x4  __attribute__((ext_vector_type(4)));

__device__ __forceinline__ float bf2f(ushort u){ return __uint_as_float(((uint32_t)u)<<16); }
__device__ __forceinline__ ushort f2bf(float f){
  uint32_t u = __float_as_uint(f);
  u += 0x7FFFu + ((u>>16)&1u);
  return (ushort)(u>>16);
}

// exact-GELU via A&S 7.1.26 erf poly (|err|<=1.5e-7): ~15 VALU vs libm erff ~30
__device__ __forceinline__ float gelu_f(float v){
  float xa = fabsf(v) * 0.70710678118654752f;
  float t  = __builtin_amdgcn_rcpf(fmaf(0.3275911f, xa, 1.0f));
  float p  = fmaf(fmaf(fmaf(fmaf(1.061405429f, t, -1.453152027f), t,
                       1.421413741f), t, -0.284496736f), t, 0.254829592f) * t;
  float e  = __expf(-xa*xa);
  float er = copysignf(fmaf(-p, e, 1.0f), v);
  return 0.5f * v * (1.0f + er);
}

// ---- LDS-tiled weight transpose+convert: dst[c*R + r] = bf16(src[r*Cc + c]) ----
__global__ __launch_bounds__(256) void transpose_cvt_all(
    const float* __restrict__ qkvw, const float* __restrict__ pw,
    const float* __restrict__ f1w,  const float* __restrict__ f2w,
    ushort* __restrict__ ws)
{
  __shared__ ushort tile[32][33];
  int bid = blockIdx.x;
  const float* src; ushort* dst; int R, Cc, b0;
  if (bid < 48)       { src = qkvw; dst = ws;          R = 128; Cc = 384; b0 = 0;   }
  else if (bid < 64)  { src = pw;   dst = ws + 49152;  R = 128; Cc = 128; b0 = 48;  }
  else if (bid < 128) { src = f1w;  dst = ws + 65536;  R = 128; Cc = 512; b0 = 64;  }
  else                { src = f2w;  dst = ws + 131072; R = 512; Cc = 128; b0 = 128; }
  int t = bid - b0;
  int tpr = Cc >> 5;                 // tiles per row of src
  int tr = t / tpr, tc = t % tpr;
  int tx = threadIdx.x & 31, ty = threadIdx.x >> 5;   // ty in 0..7
  #pragma unroll
  for (int k = 0; k < 4; k++){
    int r = tr*32 + ty + k*8;
    tile[ty + k*8][tx] = f2bf(src[(size_t)r*Cc + tc*32 + tx]);
  }
  __syncthreads();
  #pragma unroll
  for (int k = 0; k < 4; k++){
    int c = tc*32 + ty + k*8;
    dst[(size_t)c*R + tr*32 + tx] = tile[tx][ty + k*8];
  }
}

// LDS layout (ushort units), 25072 ush = 50144 B -> 3 blocks/CU:
//  [OFF_BUFA, +8704)  64x136 : xw(LN1) -> V^T [128 dims][68 toks] -> attn-out[64][136] -> xn[64][136]
//  [OFF_QK,   +15680) Q,K per head stride 40 ; P overlay per head (stride 72)
//                     -> xstage f32 [49][132] (12936 ush) + LN2 partials f32x2 (784 ush at +12936)
//                     -> hchunk[64][136] for MLP -> fout f32 [49][132] for coalesced store
//  [OFF_TBL,  +676)   rel-bias table bf16
#define OFF_BUFA 0
#define OFF_QK   8704
#define QKSTR    40
#define OFF_TBL  (OFF_QK + 8*NTOK*QKSTR)   // 24384
#define OFF_PP   (OFF_QK + 12936)
#define SMEM_SZ  25072

__global__ __launch_bounds__(256,3) void swin_block_kernel(
    const float* __restrict__ x, const float* __restrict__ n1g, const float* __restrict__ n1b,
    const ushort* __restrict__ qkv_wt, const float* __restrict__ qkvb,
    const float* __restrict__ bias_tbl, const ushort* __restrict__ proj_wt,
    const float* __restrict__ projb,
    const float* __restrict__ n2g, const float* __restrict__ n2b,
    const ushort* __restrict__ fc1_wt, const float* __restrict__ fc1b,
    const ushort* __restrict__ fc2_wt, const float* __restrict__ fc2b,
    float* __restrict__ out)
{
  __shared__ ushort smem[SMEM_SZ];

  const int tid  = threadIdx.x;
  const int wave = tid >> 6;
  const int lane = tid & 63;
  const int b_   = blockIdx.x;
  const int b    = b_ >> 6;
  const int win  = b_ & 63;
  const int wi   = win >> 3, wj = win & 7;

  const int ncol  = lane & 15;
  const int quad  = lane >> 4;
  const int koff  = quad * 8;
  const int rbase = quad * 4;
  const int l32   = lane & 31;
  const int hlf   = lane >> 5;

  // ---- init: rel-bias table only ----
  for (int i = tid; i < 676; i += 256) smem[OFF_TBL + i] = f2bf(bias_tbl[i]);

  // ---- Phase 0: LN1, float4 per lane, 32-lane (half-wave) reduce, 2 rows per wave-pass ----
  {
    const int c = l32*4;
    const float4 g4 = *(const float4*)(n1g + c);
    const float4 b4 = *(const float4*)(n1b + c);
    for (int r = wave*2 + hlf; r < NTOK; r += 8){
      int ti = r / 7, tj = r % 7;
      int hh = (wi*7 + ti + SHIFT) % HIMG;
      int ww = (wj*7 + tj + SHIFT) % HIMG;
      float4 tv = *(const float4*)(x + ((size_t)b*LTOK + hh*HIMG + ww)*DIM + c);
      float sm = tv.x + tv.y + tv.z + tv.w;
      #pragma unroll
      for (int off=16; off; off>>=1) sm += __shfl_xor(sm, off, 64);
      float mu = sm * (1.0f/128.0f);
      float d0 = tv.x-mu, d1 = tv.y-mu, d2 = tv.z-mu, d3 = tv.w-mu;
      float sq = d0*d0 + d1*d1 + d2*d2 + d3*d3;
      #pragma unroll
      for (int off=16; off; off>>=1) sq += __shfl_xor(sq, off, 64);
      float rstd = rsqrtf(sq*(1.0f/128.0f) + EPSF);
      ushort4 o;
      o.x = f2bf(d0*rstd*g4.x + b4.x);
      o.y = f2bf(d1*rstd*g4.y + b4.y);
      o.z = f2bf(d2*rstd*g4.z + b4.z);
      o.w = f2bf(d3*rstd*g4.w + b4.w);
      *(ushort4*)&smem[OFF_BUFA + r*136 + c] = o;
    }
  }
  __syncthreads();   // B1

  // ---- Phase 1: QKV GEMM (64x384, K=128); V^T goes into bufA (xw dead after afrag) ----
  {
    bf16x8 afrag[4][4];
    #pragma unroll
    for (int mt=0; mt<4; mt++)
      #pragma unroll
      for (int kb=0; kb<4; kb++)
        afrag[mt][kb] = *(const bf16x8*)&smem[OFF_BUFA + (mt*16 + ncol)*136 + kb*32 + koff];
    __syncthreads();   // B2: afrags register-resident; bufA reusable as V^T

    // zero V^T pad tokens 49..63
    for (int i = tid; i < 128*15; i += 256){
      int dd = i/15, t = 49 + i%15;
      smem[OFF_BUFA + dd*68 + t] = 0;
    }

    #pragma unroll
    for (int nt=0; nt<6; nt++){
      int c = wave*96 + nt*16 + ncol;
      int which = c >> 7, head = (c >> 5) & 3, d = c & 31;
      bf16x8 bfrag[4];
      #pragma unroll
      for (int kb=0; kb<4; kb++) bfrag[kb] = *(const bf16x8*)(qkv_wt + (size_t)c*128 + kb*32 + koff);
      float bias = qkvb[c];
      int qkb = OFF_QK + (head*2 + which)*NTOK*QKSTR + d;
      int vb  = OFF_BUFA + (head*32 + d)*68;
      #pragma unroll
      for (int mt=0; mt<4; mt++){
        f32x4 acc = {0.f,0.f,0.f,0.f};
        #pragma unroll
        for (int kb=0; kb<4; kb++)
          acc = __builtin_amdgcn_mfma_f32_16x16x32_bf16(afrag[mt][kb], bfrag[kb], acc, 0,0,0);
        #pragma unroll
        for (int r=0; r<4; r++){
          int m = mt*16 + rbase + r;
          if (m < NTOK){
            ushort v = f2bf(acc[r] + bias);
            if (which == 2) smem[vb + m] = v;
            else            smem[qkb + m*QKSTR] = v;
          }
        }
      }
    }
  }
  __syncthreads();   // B3

  float4 xpre[7];    // residual-x prefetch (written to LDS after B5)

  // ---- Phase 2: MFMA attention, wave = head ----
  {
    const int h = wave;
    const int qbase = OFF_QK + (h*2    )*NTOK*QKSTR;
    const int kbase = OFF_QK + (h*2 + 1)*NTOK*QKSTR;
    const int pbase = qbase;                       // P overlays Q+K, stride 72

    bf16x8 qf[4], kf[4];
    #pragma unroll
    for (int mt=0; mt<4; mt++) qf[mt] = *(const bf16x8*)&smem[qbase + (mt*16 + ncol)*QKSTR + koff];
    #pragma unroll
    for (int nt=0; nt<4; nt++) kf[nt] = *(const bf16x8*)&smem[kbase + (nt*16 + ncol)*QKSTR + koff];

    f32x4 s[4][4];
    #pragma unroll
    for (int mt=0; mt<4; mt++)
      #pragma unroll
      for (int nt=0; nt<4; nt++){
        f32x4 z = {0.f,0.f,0.f,0.f};
        s[mt][nt] = __builtin_amdgcn_mfma_f32_16x16x32_bf16(qf[mt], kf[nt], z, 0,0,0);
      }

    int kcol[4], rm[4];
    #pragma unroll
    for (int nt=0; nt<4; nt++){
      int k = nt*16 + ncol;
      kcol[nt] = k;
      int kc = k < NTOK ? k : 48;
      int si = kc/7, sj = kc%7;
      int sh = wi*7 + si, sw = wj*7 + sj;
      rm[nt] = (sh<49?0:(sh<53?1:2))*3 + (sw<49?0:(sw<53?1:2));
    }
    const float scale = 0.17677669529663687f;  // 1/sqrt(32)

    // softmax WITHOUT max-subtract: |S| <~ 2 here; masked lanes -> exp -> 0.
    #pragma unroll
    for (int mt=0; mt<4; mt++){
      #pragma unroll
      for (int r=0; r<4; r++){
        int m  = mt*16 + rbase + r;
        int mc = m < NTOK ? m : 48;
        int ti = mc/7, tj = mc%7;
        int habs = wi*7 + ti, wabs = wj*7 + tj;
        int rn = (habs<49?0:(habs<53?1:2))*3 + (wabs<49?0:(wabs<53?1:2));
        float sv[4];
        #pragma unroll
        for (int nt=0; nt<4; nt++){
          int k  = kcol[nt];
          int kc = k < NTOK ? k : 48;
          int si = kc/7, sj = kc%7;
          int idx = (ti - si + 6)*13 + (tj - sj + 6);
          float bias = bf2f(smem[OFF_TBL + idx*4 + h]);
          float v = s[mt][nt][r]*scale + bias + (rn == rm[nt] ? 0.f : -100.f);
          sv[nt] = (k < NTOK) ? v : -1e30f;
        }
        float sum = 0.f;
        #pragma unroll
        for (int nt=0; nt<4; nt++){ sv[nt] = __expf(sv[nt]); sum += sv[nt]; }
        #pragma unroll
        for (int off=1; off<16; off<<=1) sum += __shfl_xor(sum, off, 64);
        float rs = 1.0f/sum;
        #pragma unroll
        for (int nt=0; nt<4; nt++) s[mt][nt][r] = sv[nt]*rs;
      }
    }

    // issue residual-x prefetch here: HBM latency hides under P-store + PV
    #pragma unroll
    for (int kk=0; kk<7; kk++){
      int rr = wave*2 + hlf + kk*8;
      if (rr < NTOK){
        int ti = rr/7, tj = rr%7;
        int hh = (wi*7 + ti + SHIFT) % HIMG;
        int ww = (wj*7 + tj + SHIFT) % HIMG;
        xpre[kk] = *(const float4*)(x + ((size_t)b*LTOK + hh*HIMG + ww)*DIM + l32*4);
      }
    }

    // P store: stride 72, ALL k in [0,64) written (k>=49 exact zeros)
    #pragma unroll
    for (int mt=0; mt<4; mt++)
      #pragma unroll
      for (int r=0; r<4; r++){
        int m = mt*16 + rbase + r;
        if (m < NTOK){
          #pragma unroll
          for (int nt=0; nt<4; nt++)
            smem[pbase + m*72 + kcol[nt]] = f2bf(s[mt][nt][r]);
        }
      }

    bf16x8 vf[2][2];
    #pragma unroll
    for (int nt=0; nt<2; nt++)
      #pragma unroll
      for (int kq=0; kq<2; kq++)
        vf[nt][kq] = *(const bf16x8*)&smem[OFF_BUFA + (h*32 + nt*16 + ncol)*68 + kq*32 + koff];
    __syncthreads();   // B4: vf held; P drained; bufA free for attn-out

    f32x4 o[4][2];
    #pragma unroll
    for (int mt=0; mt<4; mt++)
      #pragma unroll
      for (int nt=0; nt<2; nt++){ f32x4 z={0.f,0.f,0.f,0.f}; o[mt][nt]=z; }

    #pragma unroll
    for (int mt=0; mt<4; mt++)
      #pragma unroll
      for (int kq=0; kq<2; kq++){
        bf16x8 pf = *(const bf16x8*)&smem[pbase + (mt*16 + ncol)*72 + kq*32 + koff];
        #pragma unroll
        for (int nt=0; nt<2; nt++)
          o[mt][nt] = __builtin_amdgcn_mfma_f32_16x16x32_bf16(pf, vf[nt][kq], o[mt][nt], 0,0,0);
      }

    #pragma unroll
    for (int mt=0; mt<4; mt++)
      #pragma unroll
      for (int nt=0; nt<2; nt++)
        #pragma unroll
        for (int r=0; r<4; r++){
          int m = mt*16 + rbase + r;
          if (m < NTOK)
            smem[OFF_BUFA + m*136 + h*32 + nt*16 + ncol] = f2bf(o[mt][nt][r]);
        }
  }
  __syncthreads();   // B5

  // ---- Phase 3a: write prefetched shifted-x rows -> xstage f32 [49][132] (P region dead) ----
  float* xstage = (float*)&smem[OFF_QK];
  #pragma unroll
  for (int kk=0; kk<7; kk++){
    int rr = wave*2 + hlf + kk*8;
    if (rr < NTOK) *(float4*)&xstage[rr*132 + l32*4] = xpre[kk];
  }

  // ---- Phase 3b: proj GEMM (64x128, K=128) + residual from xstage -> x2 in REGISTERS ----
  float x2reg[2][4][4];
  {
    bf16x8 afrag[4][4];
    #pragma unroll
    for (int mt=0; mt<4; mt++)
      #pragma unroll
      for (int kb=0; kb<4; kb++)
        afrag[mt][kb] = *(const bf16x8*)&smem[OFF_BUFA + (mt*16 + ncol)*136 + kb*32 + koff];
    __syncthreads();   // B5b: xstage visible; afrag register-resident

    #pragma unroll
    for (int nt=0; nt<2; nt++){
      int j = wave*32 + nt*16 + ncol;
      bf16x8 bfrag[4];
      #pragma unroll
      for (int kb=0; kb<4; kb++) bfrag[kb] = *(const bf16x8*)(proj_wt + (size_t)j*128 + kb*32 + koff);
      float bias = projb[j];
      #pragma unroll
      for (int mt=0; mt<4; mt++){
        f32x4 acc = {0.f,0.f,0.f,0.f};
        #pragma unroll
        for (int kb=0; kb<4; kb++)
          acc = __builtin_amdgcn_mfma_f32_16x16x32_bf16(afrag[mt][kb], bfrag[kb], acc, 0,0,0);
        #pragma unroll
        for (int r=0; r<4; r++){
          int m = mt*16 + rbase + r;
          if (m < NTOK) x2reg[nt][mt][r] = acc[r] + bias + xstage[m*132 + j];
          else          x2reg[nt][mt][r] = 0.f;
        }
      }
    }
  }

  // ---- Phase 3.5: LN2 partial sums (16-lane shfl reduce -> f32 table behind xstage) ----
  float2* pp = (float2*)&smem[OFF_PP];          // pp[m*4 + wave] = {sum, sumsq}
  #pragma unroll
  for (int mt=0; mt<4; mt++)
    #pragma unroll
    for (int r=0; r<4; r++){
      float a0 = x2reg[0][mt][r], a1 = x2reg[1][mt][r];
      float sm = a0 + a1, sq = a0*a0 + a1*a1;
      #pragma unroll
      for (int off=1; off<16; off<<=1){ sm += __shfl_xor(sm, off, 64); sq += __shfl_xor(sq, off, 64); }
      if (ncol == 0) pp[(mt*16 + rbase + r)*4 + wave] = make_float2(sm, sq);
    }
  __syncthreads();   // B6

  // ---- Phase 4: LN2 finalize + write xn (bf16) into bufA ----
  {
    const int j0 = wave*32 + ncol, j1 = j0 + 16;
    const float g0 = n2g[j0], be0 = n2b[j0], g1 = n2g[j1], be1 = n2b[j1];
    #pragma unroll
    for (int mt=0; mt<4; mt++)
      #pragma unroll
      for (int r=0; r<4; r++){
        int m = mt*16 + rbase + r;
        f32x4 pa = *(const f32x4*)&pp[m*4];
        f32x4 pb = *(const f32x4*)&pp[m*4 + 2];
        float sm = pa[0]+pa[2]+pb[0]+pb[2];
        float sq = pa[1]+pa[3]+pb[1]+pb[3];
        float mu   = sm * (1.0f/128.0f);
        float rstd = rsqrtf(sq*(1.0f/128.0f) - mu*mu + EPSF);
        smem[OFF_BUFA + m*136 + j0] = f2bf((x2reg[0][mt][r]-mu)*rstd*g0 + be0);
        smem[OFF_BUFA + m*136 + j1] = f2bf((x2reg[1][mt][r]-mu)*rstd*g1 + be1);
      }
  }
  __syncthreads();   // B7

  // ---- Phase 5: MLP tiled over 4 hidden chunks of 128; hchunk overlays Q/K region ----
  // mt-outer restructure: A-fragments loaded once per (mt,kb), reused across nt -> half the
  // stride-136 conflicted ds_read_b128s vs nt-outer.
  f32x4 o2[2][4];
  #pragma unroll
  for (int nt=0; nt<2; nt++)
    #pragma unroll
    for (int mt=0; mt<4; mt++){ f32x4 z={0.f,0.f,0.f,0.f}; o2[nt][mt]=z; }

  for (int hk=0; hk<4; hk++){
    {
      bf16x8 bfrag2[2][4];
      float  bias2[2];
      #pragma unroll
      for (int nt=0; nt<2; nt++){
        int c = hk*128 + wave*32 + nt*16 + ncol;
        #pragma unroll
        for (int kb=0; kb<4; kb++)
          bfrag2[nt][kb] = *(const bf16x8*)(fc1_wt + (size_t)c*128 + kb*32 + koff);
        bias2[nt] = fc1b[c];
      }
      #pragma unroll
      for (int mt=0; mt<4; mt++){
        bf16x8 a4[4];
        #pragma unroll
        for (int kb=0; kb<4; kb++)
          a4[kb] = *(const bf16x8*)&smem[OFF_BUFA + (mt*16 + ncol)*136 + kb*32 + koff];
        #pragma unroll
        for (int nt=0; nt<2; nt++){
          f32x4 acc = {0.f,0.f,0.f,0.f};
          #pragma unroll
          for (int kb=0; kb<4; kb++)
            acc = __builtin_amdgcn_mfma_f32_16x16x32_bf16(a4[kb], bfrag2[nt][kb], acc, 0,0,0);
          int cloc = wave*32 + nt*16 + ncol;
          #pragma unroll
          for (int r=0; r<4; r++){
            int m = mt*16 + rbase + r;
            if (mt < 3 || m < NTOK)
              smem[OFF_QK + m*136 + cloc] = f2bf(gelu_f(acc[r] + bias2[nt]));
          }
        }
      }
    }
    __syncthreads();

    {
      bf16x8 bfrag2[2][4];
      #pragma unroll
      for (int nt=0; nt<2; nt++){
        int j = wave*32 + nt*16 + ncol;
        #pragma unroll
        for (int kb=0; kb<4; kb++)
          bfrag2[nt][kb] = *(const bf16x8*)(fc2_wt + (size_t)j*512 + hk*128 + kb*32 + koff);
      }
      #pragma unroll
      for (int mt=0; mt<4; mt++){
        bf16x8 ha4[4];
        #pragma unroll
        for (int kb=0; kb<4; kb++)
          ha4[kb] = *(const bf16x8*)&smem[OFF_QK + (mt*16 + ncol)*136 + kb*32 + koff];
        #pragma unroll
        for (int nt=0; nt<2; nt++)
          #pragma unroll
          for (int kb=0; kb<4; kb++)
            o2[nt][mt] = __builtin_amdgcn_mfma_f32_16x16x32_bf16(ha4[kb], bfrag2[nt][kb], o2[nt][mt], 0,0,0);
      }
    }
    __syncthreads();   // also guards fout overlay on last iter
  }

  // ---- Final: fout = x2(reg) + fc2 + b2 into LDS f32 [49][132], then coalesced row store ----
  float* fout = (float*)&smem[OFF_QK];
  #pragma unroll
  for (int nt=0; nt<2; nt++){
    int j = wave*32 + nt*16 + ncol;
    float bias = fc2b[j];
    #pragma unroll
    for (int mt=0; mt<4; mt++){
      #pragma unroll
      for (int r=0; r<4; r++){
        int m = mt*16 + rbase + r;
        if (m < NTOK)
          fout[m*132 + j] = o2[nt][mt][r] + bias + x2reg[nt][mt][r];
      }
    }
  }
  __syncthreads();   // B8

  for (int rr = wave*2 + hlf; rr < NTOK; rr += 8){
    int ti = rr/7, tj = rr%7;
    int hh = (wi*7 + ti + SHIFT) % HIMG;
    int ww = (wj*7 + tj + SHIFT) % HIMG;
    float4 v = *(const float4*)&fout[rr*132 + l32*4];
    *(float4*)(out + ((size_t)b*LTOK + hh*HIMG + ww)*DIM + l32*4) = v;
  }
}

extern "C" void kernel_launch(void* const* d_in, const int* in_sizes, int n_in,
                              void* d_out, int out_size, void* d_ws, size_t ws_size,
                              hipStream_t stream)
{
  const float* x    = (const float*)d_in[0];
  const float* n1g  = (const float*)d_in[1];
  const float* n1b  = (const float*)d_in[2];
  const float* qkvw = (const float*)d_in[3];
  const float* qkvb = (const float*)d_in[4];
  const float* tbl  = (const float*)d_in[5];
  const float* pw   = (const float*)d_in[6];
  const float* pb   = (const float*)d_in[7];
  const float* n2g  = (const float*)d_in[8];
  const float* n2b  = (const float*)d_in[9];
  const float* f1w  = (const float*)d_in[10];
  const float* f1b  = (const float*)d_in[11];
  const float* f2w  = (const float*)d_in[12];
  const float* f2b  = (const float*)d_in[13];

  ushort* wsbase = (ushort*)d_ws;
  transpose_cvt_all<<<192, 256, 0, stream>>>(qkvw, pw, f1w, f2w, wsbase);

  swin_block_kernel<<<4096, 256, 0, stream>>>(x, n1g, n1b, wsbase, qkvb, tbl,
                                              wsbase + 49152, pb, n2g, n2b,
                                              wsbase + 65536, f1b, wsbase + 131072, f2b,
                                              (float*)d_out);
}